// Round 2
// baseline (9934.374 us; speedup 1.0000x reference)
//
#include <hip/hip_runtime.h>

// ---------------- GEMM: C[m,n] = sum_k A[m,k]*B[n,k]  (fp32, B transposed layout)
#define BM 64
#define BN 64
#define BK 16

__global__ __launch_bounds__(256) void gemm_bt_f32(const float* __restrict__ A, const float* __restrict__ B,
                                                   float* __restrict__ C, int M, int N, int K,
                                                   int lda, int ldc) {
    __shared__ float As[BK][BM + 4];
    __shared__ float Bs[BK][BN + 4];
    const int tid = threadIdx.x;
    const int m0 = blockIdx.y * BM, n0 = blockIdx.x * BN;
    const int tx = tid & 15, ty = tid >> 4;
    const int lrow = tid >> 2;          // 0..63
    const int lcol = (tid & 3) << 2;    // 0,4,8,12
    float acc[4][4] = {};
    for (int k0 = 0; k0 < K; k0 += BK) {
        float4 a4 = *(const float4*)(A + (size_t)(m0 + lrow) * lda + (k0 + lcol));
        float4 b4 = *(const float4*)(B + (size_t)(n0 + lrow) * K + (k0 + lcol));
        As[lcol + 0][lrow] = a4.x; As[lcol + 1][lrow] = a4.y;
        As[lcol + 2][lrow] = a4.z; As[lcol + 3][lrow] = a4.w;
        Bs[lcol + 0][lrow] = b4.x; Bs[lcol + 1][lrow] = b4.y;
        Bs[lcol + 2][lrow] = b4.z; Bs[lcol + 3][lrow] = b4.w;
        __syncthreads();
#pragma unroll
        for (int kk = 0; kk < BK; kk++) {
            float a[4], b[4];
#pragma unroll
            for (int i = 0; i < 4; i++) a[i] = As[kk][ty * 4 + i];
#pragma unroll
            for (int j = 0; j < 4; j++) b[j] = Bs[kk][tx * 4 + j];
#pragma unroll
            for (int i = 0; i < 4; i++)
#pragma unroll
                for (int j = 0; j < 4; j++)
                    acc[i][j] = fmaf(a[i], b[j], acc[i][j]);
        }
        __syncthreads();
    }
#pragma unroll
    for (int i = 0; i < 4; i++) {
        float4 o = make_float4(acc[i][0], acc[i][1], acc[i][2], acc[i][3]);
        *(float4*)(C + (size_t)(m0 + ty * 4 + i) * ldc + (n0 + tx * 4)) = o;
    }
}

// ---------------- RoPE in-place on Q,K columns of qkv (B,S, 3*H*D with layout (3,H,D))
__global__ __launch_bounds__(256) void rope_inplace(float* __restrict__ qkv) {
    int idx = blockIdx.x * 256 + threadIdx.x;   // over B*S*H*64 = 4194304
    int j = idx & 63;
    int h = (idx >> 6) & 15;
    int s = (idx >> 10) & 2047;
    int b = idx >> 21;
    size_t base = ((size_t)(b * 2048 + s)) * 6144 + h * 128;
    // inv_freq = 10000^(-j/64)
    float inv = expf((float)j * (-9.210340371976184f / 64.f));
    float ang = (float)s * inv;
    float c = cosf(ang), sn = sinf(ang);
    float q1 = qkv[base + j], q2 = qkv[base + j + 64];
    qkv[base + j]      = q1 * c - q2 * sn;
    qkv[base + j + 64] = q2 * c + q1 * sn;
    float k1 = qkv[base + 2048 + j], k2 = qkv[base + 2048 + j + 64];
    qkv[base + 2048 + j]      = k1 * c - k2 * sn;
    qkv[base + 2048 + j + 64] = k2 * c + k1 * sn;
}

// ---------------- Attention: one block per (b,h,q). Scores in LDS, softmax, PV.
#define ATT_SCALE 0.08838834764831845f  // 1/sqrt(128)

__global__ __launch_bounds__(256) void attn_kernel(const float* __restrict__ qkv,
                                                   float* __restrict__ O) {
    const int qi = blockIdx.x;
    const int bh = blockIdx.y;   // b*16 + h
    const int b = bh >> 4, h = bh & 15;
    const int tid = threadIdx.x;
    __shared__ float qv[128];
    __shared__ float sc[2048];
    __shared__ float red[256];
    const float* Qr = qkv + ((size_t)(b * 2048 + qi)) * 6144 + h * 128;
    if (tid < 128) qv[tid] = Qr[tid];
    __syncthreads();
    const float* Kb = qkv + (size_t)b * 2048 * 6144 + 2048 + h * 128;
    float lmax = -3.0e38f;
    for (int k = tid; k <= qi; k += 256) {
        const float4* K4 = (const float4*)(Kb + (size_t)k * 6144);
        float s4[4] = {0.f, 0.f, 0.f, 0.f};
#pragma unroll
        for (int i = 0; i < 32; i++) {
            float4 u = K4[i];
            s4[0] = fmaf(qv[4 * i + 0], u.x, s4[0]);
            s4[1] = fmaf(qv[4 * i + 1], u.y, s4[1]);
            s4[2] = fmaf(qv[4 * i + 2], u.z, s4[2]);
            s4[3] = fmaf(qv[4 * i + 3], u.w, s4[3]);
        }
        float s = ((s4[0] + s4[1]) + (s4[2] + s4[3])) * ATT_SCALE;
        sc[k] = s;
        lmax = fmaxf(lmax, s);
    }
    red[tid] = lmax;
    __syncthreads();
    for (int off = 128; off; off >>= 1) {
        if (tid < off) red[tid] = fmaxf(red[tid], red[tid + off]);
        __syncthreads();
    }
    float m = red[0];
    __syncthreads();
    float lsum = 0.f;
    for (int k = tid; k <= qi; k += 256) {
        float p = __expf(sc[k] - m);
        sc[k] = p;
        lsum += p;
    }
    red[tid] = lsum;
    __syncthreads();
    for (int off = 128; off; off >>= 1) {
        if (tid < off) red[tid] += red[tid + off];
        __syncthreads();
    }
    float denom = red[0];
    __syncthreads();
    const float* Vb = qkv + (size_t)b * 2048 * 6144 + 4096 + h * 128;
    const int d = tid & 127, part = tid >> 7;   // 2-way k-partition
    float a0 = 0.f, a1 = 0.f;
    int k = part;
    for (; k + 2 <= qi; k += 4) {
        a0 = fmaf(sc[k],     Vb[(size_t)k * 6144 + d],       a0);
        a1 = fmaf(sc[k + 2], Vb[(size_t)(k + 2) * 6144 + d], a1);
    }
    for (; k <= qi; k += 2)
        a0 = fmaf(sc[k], Vb[(size_t)k * 6144 + d], a0);
    red[tid] = a0 + a1;
    __syncthreads();
    if (tid < 128) {
        float r = (red[tid] + red[tid + 128]) / denom;
        O[((size_t)(b * 2048 + qi)) * 2048 + h * 128 + tid] = r;
    }
}

extern "C" void kernel_launch(void* const* d_in, const int* in_sizes, int n_in,
                              void* d_out, int out_size, void* d_ws, size_t ws_size,
                              hipStream_t stream) {
    const float* x     = (const float*)d_in[0];   // (2,2048,2048) fp32
    const float* w_qkv = (const float*)d_in[1];   // (6144,2048) fp32
    const float* w_o   = (const float*)d_in[2];   // (2048,2048) fp32
    float* out = (float*)d_out;                   // (2,2048,2048) fp32
    float* ws = (float*)d_ws;

    float* qkv = ws;                  // 4096*6144 = 25165824 floats (96 MB)
    float* AO  = ws + 25165824;       // 8388608 floats (32 MB)

    // 1) QKV projection: (4096,2048) x (6144,2048)^T -> qkv (ldc 6144)
    gemm_bt_f32<<<dim3(6144 / BN, 4096 / BM), 256, 0, stream>>>(x, w_qkv, qkv, 4096, 6144, 2048, 2048, 6144);
    // 2) RoPE in-place on Q,K columns of qkv
    rope_inplace<<<4194304 / 256, 256, 0, stream>>>(qkv);
    // 3) Attention -> AO (B*S, 2048)
    attn_kernel<<<dim3(2048, 32), 256, 0, stream>>>(qkv, AO);
    // 4) Output projection: (4096,2048) x (2048,2048)^T -> out
    gemm_bt_f32<<<dim3(2048 / BN, 4096 / BM), 256, 0, stream>>>(AO, w_o, out, 4096, 2048, 2048, 2048, 2048);
}

// Round 3
// 600.676 us; speedup vs baseline: 16.5387x; 16.5387x over previous
//
#include <hip/hip_runtime.h>
#include <hip/hip_bf16.h>

typedef unsigned short u16;
typedef u16 us8 __attribute__((ext_vector_type(8)));
typedef __bf16 bf8_t __attribute__((ext_vector_type(8)));
typedef float f32x4 __attribute__((ext_vector_type(4)));

__device__ __forceinline__ float b2f(u16 u) {
    return __uint_as_float(((unsigned int)u) << 16);
}
__device__ __forceinline__ u16 f2b(float f) {
    union { __hip_bfloat16 h; u16 u; } v;
    v.h = __float2bfloat16(f);
    return v.u;
}
__device__ __forceinline__ f32x4 mfma16(bf8_t a, bf8_t b, f32x4 c) {
    return __builtin_amdgcn_mfma_f32_16x16x32_bf16(a, b, c, 0, 0, 0);
}
__device__ __forceinline__ void gload_lds16(const u16* g, u16* lds_base) {
    __builtin_amdgcn_global_load_lds((const __attribute__((address_space(1))) unsigned int*)g,
                                     (__attribute__((address_space(3))) unsigned int*)lds_base,
                                     16, 0, 0);
}

// ---------------- fp32 -> bf16 convert (8 elems/thread)
__global__ __launch_bounds__(256) void f32_to_bf16(const float* __restrict__ src,
                                                   u16* __restrict__ dst, int n8) {
    int idx = blockIdx.x * 256 + threadIdx.x;
    if (idx >= n8) return;
    float4 f0 = ((const float4*)src)[idx * 2];
    float4 f1 = ((const float4*)src)[idx * 2 + 1];
    us8 o;
    o[0] = f2b(f0.x); o[1] = f2b(f0.y); o[2] = f2b(f0.z); o[3] = f2b(f0.w);
    o[4] = f2b(f1.x); o[5] = f2b(f1.y); o[6] = f2b(f1.z); o[7] = f2b(f1.w);
    ((us8*)dst)[idx] = o;
}

// ---------------- bf16 MFMA GEMM: C[m,n] = sum_k A[m,k]*B[n,k]; 128x128x32 tiles, m97-style
template<int STORE_F32>
__global__ __launch_bounds__(256) void gemm_mfma_bt(const u16* __restrict__ A, const u16* __restrict__ B,
                                                    void* __restrict__ Cout, int M, int N, int K, int ldc) {
    __shared__ u16 Alds[128 * 32];   // [m][k], contiguous (global_load_lds layout)
    __shared__ u16 Blds[128 * 32];   // [n][k]
    const int tid = threadIdx.x;
    const int lane = tid & 63, wave = tid >> 6;
    const int lm = lane & 15, lq = lane >> 4;
    const int wm = wave >> 1, wn = wave & 1;         // 2x2 wave grid, 64x64 per wave
    const int m0 = blockIdx.y * 128, n0 = blockIdx.x * 128;
    const int srow = lane >> 2;                       // 0..15 row within 16-row chunk
    const int scol = (lane & 3) * 8;                  // halfword col offset (16B)

    f32x4 acc[4][4] = {};

    for (int k0 = 0; k0 < K; k0 += 32) {
#pragma unroll
        for (int p = 0; p < 2; p++) {
            int rbase = wave * 16 + p * 64;
            gload_lds16(A + (size_t)(m0 + rbase + srow) * K + k0 + scol, &Alds[rbase * 32]);
            gload_lds16(B + (size_t)(n0 + rbase + srow) * K + k0 + scol, &Blds[rbase * 32]);
        }
        __syncthreads();
        bf8_t af[4], bf[4];
#pragma unroll
        for (int mb = 0; mb < 4; mb++)
            af[mb] = *(const bf8_t*)&Alds[(wm * 64 + mb * 16 + lm) * 32 + lq * 8];
#pragma unroll
        for (int nb = 0; nb < 4; nb++)
            bf[nb] = *(const bf8_t*)&Blds[(wn * 64 + nb * 16 + lm) * 32 + lq * 8];
#pragma unroll
        for (int mb = 0; mb < 4; mb++)
#pragma unroll
            for (int nb = 0; nb < 4; nb++)
                acc[mb][nb] = mfma16(af[mb], bf[nb], acc[mb][nb]);
        __syncthreads();
    }
#pragma unroll
    for (int mb = 0; mb < 4; mb++)
#pragma unroll
        for (int nb = 0; nb < 4; nb++)
#pragma unroll
            for (int r = 0; r < 4; r++) {
                int row = m0 + wm * 64 + mb * 16 + lq * 4 + r;
                int col = n0 + wn * 64 + nb * 16 + lm;
                if (STORE_F32)
                    ((float*)Cout)[(size_t)row * ldc + col] = acc[mb][nb][r];
                else
                    ((u16*)Cout)[(size_t)row * ldc + col] = f2b(acc[mb][nb][r]);
            }
}

// ---------------- RoPE in-place on bf16 qkv (B,S,(3,H,D))
__global__ __launch_bounds__(256) void rope_bf16(u16* __restrict__ qkv) {
    int idx = blockIdx.x * 256 + threadIdx.x;   // B*S*H*64 = 4194304
    int j = idx & 63;
    int h = (idx >> 6) & 15;
    int s = (idx >> 10) & 2047;
    int b = idx >> 21;
    size_t base = ((size_t)(b * 2048 + s)) * 6144 + h * 128;
    float inv = __expf((float)j * (-9.210340371976184f / 64.f));
    float ang = (float)s * inv;
    float sn, c;
    sincosf(ang, &sn, &c);
    float q1 = b2f(qkv[base + j]), q2 = b2f(qkv[base + j + 64]);
    qkv[base + j]      = f2b(q1 * c - q2 * sn);
    qkv[base + j + 64] = f2b(q2 * c + q1 * sn);
    float k1 = b2f(qkv[base + 2048 + j]), k2 = b2f(qkv[base + 2048 + j + 64]);
    qkv[base + 2048 + j]      = f2b(k1 * c - k2 * sn);
    qkv[base + 2048 + j + 64] = f2b(k2 * c + k1 * sn);
}

// ---------------- V transpose: qkv V part (B,S,H,D) -> VT (B,H,D,S)
__global__ __launch_bounds__(256) void transpose_v(const u16* __restrict__ qkv, u16* __restrict__ VT) {
    __shared__ u16 T[64 * 136];
    const int tid = threadIdx.x;
    const int s0 = blockIdx.x * 64;
    const int bh = blockIdx.y;
    const int b = bh >> 4, h = bh & 15;
#pragma unroll
    for (int p = 0; p < 4; p++) {
        int sl = p * 16 + (tid >> 4);
        int d0 = (tid & 15) * 8;
        *(us8*)&T[sl * 136 + d0] =
            *(const us8*)(qkv + ((size_t)(b * 2048 + s0 + sl)) * 6144 + 4096 + h * 128 + d0);
    }
    __syncthreads();
#pragma unroll
    for (int p = 0; p < 4; p++) {
        int idx = p * 256 + tid;
        int d = idx & 127;
        int sg = idx >> 7;       // 0..7
        us8 v;
#pragma unroll
        for (int i = 0; i < 8; i++) v[i] = T[(sg * 8 + i) * 136 + d];
        *(us8*)&VT[((size_t)bh * 128 + d) * 2048 + s0 + sg * 8] = v;
    }
}

// ---------------- Flash attention: block = (q-tile 64, bh); 4 waves x 16 q-rows
#define ATT_SCALE 0.08838834764831845f

__global__ __launch_bounds__(256) void attn_flash(const u16* __restrict__ qkv, const u16* __restrict__ VT,
                                                  u16* __restrict__ AO) {
    const int qt = blockIdx.x;          // 0..31
    const int bh = blockIdx.y;          // 0..31
    const int b = bh >> 4, h = bh & 15;
    const int tid = threadIdx.x, lane = tid & 63, wave = tid >> 6;
    const int lm = lane & 15, lq = lane >> 4;
    const int q0 = qt * 64;

    __shared__ u16 Kt[64 * 136];        // [kpos][d], stride 136 halfwords
    __shared__ u16 Vt[128 * 72];        // [d][kpos], stride 72
    __shared__ u16 Pl[4][16 * 72];      // per-wave P [q][kpos], stride 72

    // Q fragments in registers (RoPE already applied)
    bf8_t qf[4];
    {
        const u16* Qrow = qkv + ((size_t)(b * 2048 + q0 + wave * 16 + lm)) * 6144 + h * 128;
#pragma unroll
        for (int ks = 0; ks < 4; ks++)
            qf[ks] = *(const bf8_t*)(Qrow + ks * 32 + lq * 8);
    }

    f32x4 Of[8] = {};
    float mrun[4], lrun[4];
#pragma unroll
    for (int r = 0; r < 4; r++) { mrun[r] = -3.0e38f; lrun[r] = 0.f; }

    const u16* Kbase = qkv + (size_t)b * 2048 * 6144 + 2048 + h * 128;
    const u16* VTbase = VT + (size_t)bh * 128 * 2048;

    for (int kt = 0; kt <= qt; kt++) {
        const int k0 = kt * 64;
        __syncthreads();
#pragma unroll
        for (int p = 0; p < 4; p++) {
            int r = p * 16 + (tid >> 4);
            int c = (tid & 15) * 8;
            *(us8*)&Kt[r * 136 + c] = *(const us8*)(Kbase + (size_t)(k0 + r) * 6144 + c);
        }
#pragma unroll
        for (int p = 0; p < 4; p++) {
            int r = p * 32 + (tid >> 3);
            int c = (tid & 7) * 8;
            *(us8*)&Vt[r * 72 + c] = *(const us8*)(VTbase + (size_t)r * 2048 + k0 + c);
        }
        __syncthreads();

        // S = Q K^T for this wave's 16 q-rows x 64 kpos
        float sv[4][4];
#pragma unroll
        for (int nb = 0; nb < 4; nb++) {
            f32x4 a = {};
#pragma unroll
            for (int ks = 0; ks < 4; ks++) {
                bf8_t kf = *(const bf8_t*)&Kt[(nb * 16 + lm) * 136 + ks * 32 + lq * 8];
                a = mfma16(qf[ks], kf, a);
            }
#pragma unroll
            for (int r = 0; r < 4; r++) sv[nb][r] = a[r] * ATT_SCALE;
        }
        if (kt == qt) {   // causal mask on diagonal tile
#pragma unroll
            for (int nb = 0; nb < 4; nb++) {
                int kp = nb * 16 + lm;
#pragma unroll
                for (int r = 0; r < 4; r++)
                    if (kp > wave * 16 + lq * 4 + r) sv[nb][r] = -3.0e38f;
            }
        }
        // row max (rows = lq*4+r, spread over 16 lanes)
        float tmax[4];
#pragma unroll
        for (int r = 0; r < 4; r++)
            tmax[r] = fmaxf(fmaxf(sv[0][r], sv[1][r]), fmaxf(sv[2][r], sv[3][r]));
#pragma unroll
        for (int m = 1; m <= 8; m <<= 1)
#pragma unroll
            for (int r = 0; r < 4; r++)
                tmax[r] = fmaxf(tmax[r], __shfl_xor(tmax[r], m, 64));
        float mnew[4], alpha[4], rsum[4];
#pragma unroll
        for (int r = 0; r < 4; r++) {
            mnew[r] = fmaxf(mrun[r], tmax[r]);
            alpha[r] = __expf(mrun[r] - mnew[r]);
            rsum[r] = 0.f;
        }
#pragma unroll
        for (int nb = 0; nb < 4; nb++)
#pragma unroll
            for (int r = 0; r < 4; r++) {
                float p = __expf(sv[nb][r] - mnew[r]);
                rsum[r] += p;
                Pl[wave][(lq * 4 + r) * 72 + nb * 16 + lm] = f2b(p);
            }
#pragma unroll
        for (int m = 1; m <= 8; m <<= 1)
#pragma unroll
            for (int r = 0; r < 4; r++)
                rsum[r] += __shfl_xor(rsum[r], m, 64);
#pragma unroll
        for (int r = 0; r < 4; r++) {
            lrun[r] = lrun[r] * alpha[r] + rsum[r];
            mrun[r] = mnew[r];
        }
        // rescale O (rows match lq*4+r)
#pragma unroll
        for (int db = 0; db < 8; db++)
#pragma unroll
            for (int r = 0; r < 4; r++) Of[db][r] *= alpha[r];
        // PV: P (16xq x 64k) x V^T (128d x 64k)
#pragma unroll
        for (int kk = 0; kk < 2; kk++) {
            bf8_t pf = *(const bf8_t*)&Pl[wave][lm * 72 + kk * 32 + lq * 8];
#pragma unroll
            for (int db = 0; db < 8; db++) {
                bf8_t vf = *(const bf8_t*)&Vt[(db * 16 + lm) * 72 + kk * 32 + lq * 8];
                Of[db] = mfma16(pf, vf, Of[db]);
            }
        }
    }
    // epilogue: normalize and store bf16 to AO (B,S,HID)
    float inv[4];
#pragma unroll
    for (int r = 0; r < 4; r++) inv[r] = 1.f / lrun[r];
#pragma unroll
    for (int db = 0; db < 8; db++)
#pragma unroll
        for (int r = 0; r < 4; r++) {
            int qrow = q0 + wave * 16 + lq * 4 + r;
            int col = h * 128 + db * 16 + lm;
            AO[(size_t)(b * 2048 + qrow) * 2048 + col] = f2b(Of[db][r] * inv[r]);
        }
}

extern "C" void kernel_launch(void* const* d_in, const int* in_sizes, int n_in,
                              void* d_out, int out_size, void* d_ws, size_t ws_size,
                              hipStream_t stream) {
    const float* x     = (const float*)d_in[0];   // (2,2048,2048) fp32
    const float* w_qkv = (const float*)d_in[1];   // (6144,2048) fp32
    const float* w_o   = (const float*)d_in[2];   // (2048,2048) fp32
    float* out = (float*)d_out;                   // (2,2048,2048) fp32
    u16* ws = (u16*)d_ws;

    u16* qkvb  = ws;                    // 25,165,824
    u16* VT    = ws + 25165824;         //  8,388,608
    u16* AO    = ws + 33554432;         //  8,388,608
    u16* xb    = ws + 41943040;         //  8,388,608
    u16* wqkvb = ws + 50331648;         // 12,582,912
    u16* wob   = ws + 62914560;         //  4,194,304  (total = 128 MiB)

    // 0) convert inputs to bf16
    f32_to_bf16<<<4096, 256, 0, stream>>>(x, xb, 1048576);
    f32_to_bf16<<<6144, 256, 0, stream>>>(w_qkv, wqkvb, 1572864);
    f32_to_bf16<<<2048, 256, 0, stream>>>(w_o, wob, 524288);
    // 1) QKV projection (bf16 out, ldc 6144)
    gemm_mfma_bt<0><<<dim3(48, 32), 256, 0, stream>>>(xb, wqkvb, qkvb, 4096, 6144, 2048, 6144);
    // 2) RoPE in-place on Q,K
    rope_bf16<<<16384, 256, 0, stream>>>(qkvb);
    // 3) V transpose -> (B,H,D,S)
    transpose_v<<<dim3(32, 32), 256, 0, stream>>>(qkvb, VT);
    // 4) flash attention -> AO (B,S,HID) bf16
    attn_flash<<<dim3(32, 32), 256, 0, stream>>>(qkvb, VT, AO);
    // 5) output projection (fp32 out)
    gemm_mfma_bt<1><<<dim3(16, 32), 256, 0, stream>>>(AO, wob, out, 4096, 2048, 2048, 2048);
}

// Round 4
// 423.202 us; speedup vs baseline: 23.4743x; 1.4194x over previous
//
#include <hip/hip_runtime.h>
#include <hip/hip_bf16.h>

typedef unsigned short u16;
typedef unsigned long long u64;
typedef u16 us8 __attribute__((ext_vector_type(8)));
typedef __bf16 bf8_t __attribute__((ext_vector_type(8)));
typedef float f32x4 __attribute__((ext_vector_type(4)));

__device__ __forceinline__ float b2f(u16 u) {
    return __uint_as_float(((unsigned int)u) << 16);
}
__device__ __forceinline__ u16 f2b(float f) {
    union { __hip_bfloat16 h; u16 u; } v;
    v.h = __float2bfloat16(f);
    return v.u;
}
__device__ __forceinline__ f32x4 mfma16(bf8_t a, bf8_t b, f32x4 c) {
    return __builtin_amdgcn_mfma_f32_16x16x32_bf16(a, b, c, 0, 0, 0);
}
__device__ __forceinline__ void gload_lds16(const u16* g, u16* lds_base) {
    __builtin_amdgcn_global_load_lds((const __attribute__((address_space(1))) unsigned int*)g,
                                     (__attribute__((address_space(3))) unsigned int*)lds_base,
                                     16, 0, 0);
}

// ---------------- fp32 -> bf16 convert (8 elems/thread)
__global__ __launch_bounds__(256) void f32_to_bf16(const float* __restrict__ src,
                                                   u16* __restrict__ dst, int n8) {
    int idx = blockIdx.x * 256 + threadIdx.x;
    if (idx >= n8) return;
    float4 f0 = ((const float4*)src)[idx * 2];
    float4 f1 = ((const float4*)src)[idx * 2 + 1];
    us8 o;
    o[0] = f2b(f0.x); o[1] = f2b(f0.y); o[2] = f2b(f0.z); o[3] = f2b(f0.w);
    o[4] = f2b(f1.x); o[5] = f2b(f1.y); o[6] = f2b(f1.z); o[7] = f2b(f1.w);
    ((us8*)dst)[idx] = o;
}

// ---------------- bf16 MFMA GEMM: C[m,n] = sum_k A[m,k]*B[n,k]; 128x128x32 tiles
template<int STORE_F32>
__global__ __launch_bounds__(256) void gemm_mfma_bt(const u16* __restrict__ A, const u16* __restrict__ B,
                                                    void* __restrict__ Cout, int M, int N, int K, int ldc) {
    __shared__ u16 Alds[128 * 32];
    __shared__ u16 Blds[128 * 32];
    const int tid = threadIdx.x;
    const int lane = tid & 63, wave = tid >> 6;
    const int lm = lane & 15, lq = lane >> 4;
    const int wm = wave >> 1, wn = wave & 1;
    const int m0 = blockIdx.y * 128, n0 = blockIdx.x * 128;
    const int srow = lane >> 2;
    const int scol = (lane & 3) * 8;

    f32x4 acc[4][4] = {};

    for (int k0 = 0; k0 < K; k0 += 32) {
#pragma unroll
        for (int p = 0; p < 2; p++) {
            int rbase = wave * 16 + p * 64;
            gload_lds16(A + (size_t)(m0 + rbase + srow) * K + k0 + scol, &Alds[rbase * 32]);
            gload_lds16(B + (size_t)(n0 + rbase + srow) * K + k0 + scol, &Blds[rbase * 32]);
        }
        __syncthreads();
        bf8_t af[4], bf[4];
#pragma unroll
        for (int mb = 0; mb < 4; mb++)
            af[mb] = *(const bf8_t*)&Alds[(wm * 64 + mb * 16 + lm) * 32 + lq * 8];
#pragma unroll
        for (int nb = 0; nb < 4; nb++)
            bf[nb] = *(const bf8_t*)&Blds[(wn * 64 + nb * 16 + lm) * 32 + lq * 8];
#pragma unroll
        for (int mb = 0; mb < 4; mb++)
#pragma unroll
            for (int nb = 0; nb < 4; nb++)
                acc[mb][nb] = mfma16(af[mb], bf[nb], acc[mb][nb]);
        __syncthreads();
    }
#pragma unroll
    for (int mb = 0; mb < 4; mb++)
#pragma unroll
        for (int nb = 0; nb < 4; nb++)
#pragma unroll
            for (int r = 0; r < 4; r++) {
                int row = m0 + wm * 64 + mb * 16 + lq * 4 + r;
                int col = n0 + wn * 64 + nb * 16 + lm;
                if (STORE_F32)
                    ((float*)Cout)[(size_t)row * ldc + col] = acc[mb][nb][r];
                else
                    ((u16*)Cout)[(size_t)row * ldc + col] = f2b(acc[mb][nb][r]);
            }
}

// ---------------- RoPE in-place on bf16 qkv (B,S,(3,H,D))
__global__ __launch_bounds__(256) void rope_bf16(u16* __restrict__ qkv) {
    int idx = blockIdx.x * 256 + threadIdx.x;
    int j = idx & 63;
    int h = (idx >> 6) & 15;
    int s = (idx >> 10) & 2047;
    int b = idx >> 21;
    size_t base = ((size_t)(b * 2048 + s)) * 6144 + h * 128;
    float inv = __expf((float)j * (-9.210340371976184f / 64.f));
    float ang = (float)s * inv;
    float sn, c;
    sincosf(ang, &sn, &c);
    float q1 = b2f(qkv[base + j]), q2 = b2f(qkv[base + j + 64]);
    qkv[base + j]      = f2b(q1 * c - q2 * sn);
    qkv[base + j + 64] = f2b(q2 * c + q1 * sn);
    float k1 = b2f(qkv[base + 2048 + j]), k2 = b2f(qkv[base + 2048 + j + 64]);
    qkv[base + 2048 + j]      = f2b(k1 * c - k2 * sn);
    qkv[base + 2048 + j + 64] = f2b(k2 * c + k1 * sn);
}

// ---------------- V transpose: qkv V part (B,S,H,D) -> VT (B,H,D,S)
__global__ __launch_bounds__(256) void transpose_v(const u16* __restrict__ qkv, u16* __restrict__ VT) {
    __shared__ u16 T[64 * 136];
    const int tid = threadIdx.x;
    const int s0 = blockIdx.x * 64;
    const int bh = blockIdx.y;
    const int b = bh >> 4, h = bh & 15;
#pragma unroll
    for (int p = 0; p < 4; p++) {
        int sl = p * 16 + (tid >> 4);
        int d0 = (tid & 15) * 8;
        *(us8*)&T[sl * 136 + d0] =
            *(const us8*)(qkv + ((size_t)(b * 2048 + s0 + sl)) * 6144 + 4096 + h * 128 + d0);
    }
    __syncthreads();
#pragma unroll
    for (int p = 0; p < 4; p++) {
        int idx = p * 256 + tid;
        int d = idx & 127;
        int sg = idx >> 7;
        us8 v;
#pragma unroll
        for (int i = 0; i < 8; i++) v[i] = T[(sg * 8 + i) * 136 + d];
        *(us8*)&VT[((size_t)bh * 128 + d) * 2048 + s0 + sg * 8] = v;
    }
}

// ---------------- Flash attention v2: S^T trick + register-shuffle P transpose
// block = (bh, q-tile 64 rows, LPT-reversed); 4 waves, each owns 16 q (q = wave*16 + lm)
#define ATT_SCALE 0.08838834764831845f

__global__ __launch_bounds__(256) void attn_flash(const u16* __restrict__ qkv, const u16* __restrict__ VT,
                                                  u16* __restrict__ AO) {
    const int bh = blockIdx.x;
    const int qt = 31 - blockIdx.y;      // heaviest blocks first (LPT)
    const int b = bh >> 4, h = bh & 15;
    const int tid = threadIdx.x, lane = tid & 63, wave = tid >> 6;
    const int lm = lane & 15, lq = lane >> 4;
    const int q0 = qt * 64;

    __shared__ u16 Kt[64 * 136];        // [kpos][d]
    __shared__ u16 Vt[128 * 72];        // [d][kpos]

    // Q fragments (B-operand: B[n=q=lm][kdim]), RoPE already applied
    bf8_t qf[4];
    {
        const u16* Qrow = qkv + ((size_t)(b * 2048 + q0 + wave * 16 + lm)) * 6144 + h * 128;
#pragma unroll
        for (int ks = 0; ks < 4; ks++)
            qf[ks] = *(const bf8_t*)(Qrow + ks * 32 + lq * 8);
    }

    f32x4 Of[8] = {};                    // O^T accum: D[m=d][n=q]
    float mrun = -3.0e38f, lrun = 0.f;   // per-lane state for q = lm (replicated over lq)

    const u16* Kbase = qkv + (size_t)b * 2048 * 6144 + 2048 + h * 128;
    const u16* VTbase = VT + (size_t)bh * 128 * 2048;

    // staging coords
    const int krow = tid >> 4;          // 0..15
    const int kcol = (tid & 15) * 8;
    const int vrow = tid >> 3;          // 0..31
    const int vcol = (tid & 7) * 8;

    us8 kreg[4], vreg[4];
#pragma unroll
    for (int p = 0; p < 4; p++) {
        kreg[p] = *(const us8*)(Kbase + (size_t)(p * 16 + krow) * 6144 + kcol);
        vreg[p] = *(const us8*)(VTbase + (size_t)(p * 32 + vrow) * 2048 + vcol);
    }

    for (int kt = 0; kt <= qt; kt++) {
        __syncthreads();
#pragma unroll
        for (int p = 0; p < 4; p++) {
            *(us8*)&Kt[(p * 16 + krow) * 136 + kcol] = kreg[p];
            *(us8*)&Vt[(p * 32 + vrow) * 72 + vcol] = vreg[p];
        }
        __syncthreads();
        // prefetch next tile (clamped; extra reload of last tile is discarded)
        {
            int kn = (kt + 1 <= qt ? kt + 1 : qt) * 64;
#pragma unroll
            for (int p = 0; p < 4; p++) {
                kreg[p] = *(const us8*)(Kbase + (size_t)(kn + p * 16 + krow) * 6144 + kcol);
                vreg[p] = *(const us8*)(VTbase + (size_t)(p * 32 + vrow) * 2048 + kn + vcol);
            }
        }

        // S^T = K · Q^T : per lane holds S[q=lm][k = nb*16 + lq*4 + r]
        float sv[4][4];
#pragma unroll
        for (int nb = 0; nb < 4; nb++) {
            f32x4 a = {};
#pragma unroll
            for (int ks = 0; ks < 4; ks++) {
                bf8_t kf = *(const bf8_t*)&Kt[(nb * 16 + lm) * 136 + ks * 32 + lq * 8];
                a = mfma16(kf, qf[ks], a);
            }
#pragma unroll
            for (int r = 0; r < 4; r++) sv[nb][r] = a[r] * ATT_SCALE;
        }
        if (kt == qt) {   // causal: mask k_local > q_local
            int qloc = wave * 16 + lm;
#pragma unroll
            for (int nb = 0; nb < 4; nb++)
#pragma unroll
                for (int r = 0; r < 4; r++)
                    if (nb * 16 + lq * 4 + r > qloc) sv[nb][r] = -3.0e38f;
        }
        // online softmax (per-lane single q; reduce across the 4 lq-replicas)
        float mx = -3.0e38f;
#pragma unroll
        for (int nb = 0; nb < 4; nb++)
#pragma unroll
            for (int r = 0; r < 4; r++) mx = fmaxf(mx, sv[nb][r]);
        mx = fmaxf(mx, __shfl_xor(mx, 16, 64));
        mx = fmaxf(mx, __shfl_xor(mx, 32, 64));
        float mnew = fmaxf(mrun, mx);
        float alpha = __expf(mrun - mnew);
        float rs = 0.f;
        u64 pk[4];
#pragma unroll
        for (int nb = 0; nb < 4; nb++) {
            float e0 = __expf(sv[nb][0] - mnew), e1 = __expf(sv[nb][1] - mnew);
            float e2 = __expf(sv[nb][2] - mnew), e3 = __expf(sv[nb][3] - mnew);
            rs += (e0 + e1) + (e2 + e3);
            unsigned int lo = (unsigned int)f2b(e0) | ((unsigned int)f2b(e1) << 16);
            unsigned int hi = (unsigned int)f2b(e2) | ((unsigned int)f2b(e3) << 16);
            pk[nb] = (u64)lo | ((u64)hi << 32);
        }
        rs += __shfl_xor(rs, 16, 64);
        rs += __shfl_xor(rs, 32, 64);
        lrun = lrun * alpha + rs;
        mrun = mnew;
#pragma unroll
        for (int db = 0; db < 8; db++)
#pragma unroll
            for (int r = 0; r < 4; r++) Of[db][r] *= alpha;

        // P^T -> A-layout fragments via shuffles; O^T += V^T · P
        const int slo = ((lq & 1) * 2) * 16 + lm;
        const int shi = slo + 16;
        const bool sel = (lq >> 1) != 0;
#pragma unroll
        for (int kk = 0; kk < 2; kk++) {
            u64 lo0 = __shfl(pk[2 * kk + 0], slo, 64);
            u64 lo1 = __shfl(pk[2 * kk + 1], slo, 64);
            u64 hi0 = __shfl(pk[2 * kk + 0], shi, 64);
            u64 hi1 = __shfl(pk[2 * kk + 1], shi, 64);
            union { u64 v[2]; bf8_t f; } pf;
            pf.v[0] = sel ? lo1 : lo0;
            pf.v[1] = sel ? hi1 : hi0;
#pragma unroll
            for (int db = 0; db < 8; db++) {
                bf8_t vf = *(const bf8_t*)&Vt[(db * 16 + lm) * 72 + kk * 32 + lq * 8];
                Of[db] = mfma16(vf, pf.f, Of[db]);
            }
        }
    }
    // epilogue: normalize, store O^T -> AO (B,S,HID); 4 consecutive d per store
    float invl = 1.f / lrun;
    size_t rowbase = (size_t)(b * 2048 + q0 + wave * 16 + lm) * 2048 + h * 128;
#pragma unroll
    for (int db = 0; db < 8; db++) {
        ushort4 o;
        o.x = f2b(Of[db][0] * invl);
        o.y = f2b(Of[db][1] * invl);
        o.z = f2b(Of[db][2] * invl);
        o.w = f2b(Of[db][3] * invl);
        *(ushort4*)(AO + rowbase + db * 16 + lq * 4) = o;
    }
}

extern "C" void kernel_launch(void* const* d_in, const int* in_sizes, int n_in,
                              void* d_out, int out_size, void* d_ws, size_t ws_size,
                              hipStream_t stream) {
    const float* x     = (const float*)d_in[0];
    const float* w_qkv = (const float*)d_in[1];
    const float* w_o   = (const float*)d_in[2];
    float* out = (float*)d_out;
    u16* ws = (u16*)d_ws;

    u16* qkvb  = ws;                    // 25,165,824
    u16* VT    = ws + 25165824;         //  8,388,608
    u16* AO    = ws + 33554432;         //  8,388,608
    u16* xb    = ws + 41943040;         //  8,388,608
    u16* wqkvb = ws + 50331648;         // 12,582,912
    u16* wob   = ws + 62914560;         //  4,194,304

    f32_to_bf16<<<4096, 256, 0, stream>>>(x, xb, 1048576);
    f32_to_bf16<<<6144, 256, 0, stream>>>(w_qkv, wqkvb, 1572864);
    f32_to_bf16<<<2048, 256, 0, stream>>>(w_o, wob, 524288);
    gemm_mfma_bt<0><<<dim3(48, 32), 256, 0, stream>>>(xb, wqkvb, qkvb, 4096, 6144, 2048, 6144);
    rope_bf16<<<16384, 256, 0, stream>>>(qkvb);
    transpose_v<<<dim3(32, 32), 256, 0, stream>>>(qkvb, VT);
    attn_flash<<<dim3(32, 32), 256, 0, stream>>>(qkvb, VT, AO);
    gemm_mfma_bt<1><<<dim3(16, 32), 256, 0, stream>>>(AO, wob, out, 4096, 2048, 2048, 2048);
}